// Round 7
// baseline (304.018 us; speedup 1.0000x reference)
//
#include <hip/hip_runtime.h>
#include <hip/hip_bf16.h>

typedef short bf16x4 __attribute__((ext_vector_type(4)));
typedef short bf16x8 __attribute__((ext_vector_type(8)));
typedef float fp32x4 __attribute__((ext_vector_type(4)));

#define MFMA16(a, b, c) __builtin_amdgcn_mfma_f32_16x16x32_bf16(a, b, c, 0, 0, 0)

static __device__ __forceinline__ short f2bf(float f) {
    unsigned int b = __float_as_uint(f);
    b += 0x7fffu + ((b >> 16) & 1u);   // RNE
    return (short)(b >> 16);
}

// async global->LDS, 16B per lane. LDS dest must be wave-uniform base + lane*16.
static __device__ __forceinline__ void gld16(const void* g, void* l) {
    __builtin_amdgcn_global_load_lds(
        (const __attribute__((address_space(1))) void*)g,
        (__attribute__((address_space(3))) void*)l, 16, 0, 0);
}

// ---------------------------------------------------------------------------
// Prepass. z<4: W[k][n] fp32 -> WbT[n][k] bf16 (64x64 tiles via LDS).
// z==4/5: convert Q/K fp32 -> bf16 flat (for global_load_lds GEMM staging).
// grid (16,16,nz), block 256.
// ---------------------------------------------------------------------------
__global__ __launch_bounds__(256) void prepass(
    const float* __restrict__ W0, const float* __restrict__ W1,
    const float* __restrict__ W2, const float* __restrict__ W3,
    short* __restrict__ wbt,
    const float* __restrict__ Qf, const float* __restrict__ Kf,
    short* __restrict__ xq, short* __restrict__ xk)
{
    __shared__ short t[64][68];
    const int tid = threadIdx.x;
    const int z = blockIdx.z;

    if (z >= 4) {                       // convert path
        const float* src = (z == 4) ? Qf : Kf;
        short* dst = (z == 4) ? xq : xk;
        int bid = blockIdx.y * 16 + blockIdx.x;
        int base = bid * 16384 + tid * 4;
#pragma unroll
        for (int p = 0; p < 16; ++p) {
            int idx = base + p * 1024;
            fp32x4 f = *(const fp32x4*)&src[idx];
            bf16x4 s;
#pragma unroll
            for (int i = 0; i < 4; ++i) s[i] = f2bf(f[i]);
            *(bf16x4*)&dst[idx] = s;
        }
        return;
    }

    const float* W = (z == 0) ? W0 : (z == 1) ? W1 : (z == 2) ? W2 : W3;
    short* dst = wbt + (size_t)z * 1024 * 1024;
    const int k0 = blockIdx.x * 64, n0 = blockIdx.y * 64;

#pragma unroll
    for (int p = 0; p < 4; ++p) {
        int c = p * 256 + tid;
        int kr = c >> 4, seg = c & 15;
        fp32x4 f = *(const fp32x4*)&W[(k0 + kr) * 1024 + n0 + seg * 4];
#pragma unroll
        for (int i = 0; i < 4; ++i) t[kr][seg * 4 + i] = f2bf(f[i]);
    }
    __syncthreads();
#pragma unroll
    for (int p = 0; p < 2; ++p) {
        int c = p * 256 + tid;
        int nr = c >> 3, ks = c & 7;
        bf16x8 v;
#pragma unroll
        for (int i = 0; i < 8; ++i) v[i] = t[ks * 8 + i][nr];
        *(bf16x8*)&dst[(n0 + nr) * 1024 + k0 + ks * 8] = v;
    }
}

// ---------------------------------------------------------------------------
// 128x128-tile GEMM, m97 recipe: global_load_lds(16B) staging into PACKED
// [row][32] LDS (no padding - required by global_load_lds lane-linear dest).
// A is bf16 (abf=1, async) or fp32 (manual convert staging). B = WbT bf16,
// always async. Epilogue: (acc+bias)*osc; HEADED -> bf16 [B,H,S,Dh], else
// fp32 flat. 4 waves x 4x4 16x16x32 subtiles, BK=32.
// ---------------------------------------------------------------------------
struct GArgs {
    const void* X[3];
    const short* W;          // WbT base, +z*1M
    const float* bias[3];
    void* out[3];
    int abf[3];
    float osc[3];
};

template <bool HEADED>
__global__ __launch_bounds__(256) void gemm128(GArgs ga)
{
    __shared__ __align__(16) short lds_a[128 * 32];
    __shared__ __align__(16) short lds_b[128 * 32];

    const int tid  = threadIdx.x;
    const int lane = tid & 63;
    const int wv   = tid >> 6;
    const int l15  = lane & 15;
    const int quad = lane >> 4;
    const int wm   = (wv >> 1) * 64;
    const int wn   = (wv & 1) * 64;
    const int z    = blockIdx.z;
    const int m0   = blockIdx.y * 128;
    const int n0   = blockIdx.x * 128;

    const short* W    = ga.W + (size_t)z * 1024 * 1024;
    const float* bias = ga.bias[z];
    const int    abf  = ga.abf[z];
    const float  osc  = ga.osc[z];
    void* outv        = ga.out[z];

    fp32x4 acc[4][4];
#pragma unroll
    for (int i = 0; i < 4; ++i)
#pragma unroll
        for (int j = 0; j < 4; ++j)
#pragma unroll
            for (int r = 0; r < 4; ++r) acc[i][j][r] = 0.f;

    for (int k0 = 0; k0 < 1024; k0 += 32) {
        __syncthreads();
        if (abf) {
            const short* X = (const short*)ga.X[z];
#pragma unroll
            for (int r = 0; r < 2; ++r) {
                int e = r * 256 + tid;
                gld16(&X[(m0 + (e >> 2)) * 1024 + k0 + (e & 3) * 8],
                      &lds_a[e * 8]);
            }
        } else {
            const float* X = (const float*)ga.X[z];
#pragma unroll
            for (int p = 0; p < 4; ++p) {
                int e = p * 256 + tid, row = e >> 3, sg = e & 7;
                fp32x4 f = *(const fp32x4*)&X[(m0 + row) * 1024 + k0 + sg * 4];
                bf16x4 s;
#pragma unroll
                for (int i = 0; i < 4; ++i) s[i] = f2bf(f[i]);
                *(bf16x4*)&lds_a[row * 32 + sg * 4] = s;
            }
        }
#pragma unroll
        for (int r = 0; r < 2; ++r) {
            int e = r * 256 + tid;
            gld16(&W[(n0 + (e >> 2)) * 1024 + k0 + (e & 3) * 8],
                  &lds_b[e * 8]);
        }
        __syncthreads();   // drains vmcnt (async loads) + lgkm

        bf16x8 af[4], bf[4];
#pragma unroll
        for (int i = 0; i < 4; ++i)
            af[i] = *(bf16x8*)&lds_a[(wm + i * 16 + l15) * 32 + quad * 8];
#pragma unroll
        for (int j = 0; j < 4; ++j)
            bf[j] = *(bf16x8*)&lds_b[(wn + j * 16 + l15) * 32 + quad * 8];
#pragma unroll
        for (int i = 0; i < 4; ++i)
#pragma unroll
            for (int j = 0; j < 4; ++j)
                acc[i][j] = MFMA16(af[i], bf[j], acc[i][j]);
    }

#pragma unroll
    for (int i = 0; i < 4; ++i)
#pragma unroll
        for (int j = 0; j < 4; ++j)
#pragma unroll
            for (int r = 0; r < 4; ++r) {
                int row = m0 + wm + i * 16 + quad * 4 + r;
                int col = n0 + wn + j * 16 + l15;
                float v = (acc[i][j][r] + bias[col]) * osc;
                if (HEADED) {
                    int b = row >> 11, s = row & 2047;
                    int h = col >> 6,  dh = col & 63;
                    ((short*)outv)[(((b * 16) + h) * 2048 + s) * 64 + dh] = f2bf(v);
                } else {
                    ((float*)outv)[row * 1024 + col] = v;
                }
            }
}

// ---------------------------------------------------------------------------
// Flash attention, max-free softmax, Q pre-scaled by 0.125*log2e so
// P = exp2(S) directly. Grid (16 q-blocks, 32 bh), 4 waves x 32 q rows.
// 64-key chunks. V^T staged via coalesced column reads (2-way-conflict LDS
// writes). P round-trip per-wave LDS with threadfence (no 3rd barrier).
// ---------------------------------------------------------------------------
__global__ __launch_bounds__(256) void attention128(
    const short* __restrict__ q, const short* __restrict__ k,
    const short* __restrict__ v, short* __restrict__ ctx)
{
    __shared__ __align__(16) short lds_k[64 * 74];       // [key][dh]
    __shared__ __align__(16) short lds_vt[64 * 74];      // [dh][key]
    __shared__ __align__(16) short lds_p[8 * 16 * 74];   // [wave*2+qt][q][key]

    const int tid  = threadIdx.x;
    const int lane = tid & 63;
    const int wv   = tid >> 6;
    const int l15  = lane & 15;
    const int quad = lane >> 4;
    const int bh   = blockIdx.y;
    const int q0   = blockIdx.x * 128 + wv * 32;

    const short* qb = q + (size_t)bh * 2048 * 64;
    const short* kb = k + (size_t)bh * 2048 * 64;
    const short* vb = v + (size_t)bh * 2048 * 64;

    bf16x8 qf[2][2];
#pragma unroll
    for (int qt = 0; qt < 2; ++qt)
#pragma unroll
        for (int h2 = 0; h2 < 2; ++h2)
            qf[qt][h2] = *(const bf16x8*)
                &qb[(q0 + qt * 16 + l15) * 64 + h2 * 32 + quad * 8];

    fp32x4 O[2][4];
    float rs[2][4];
#pragma unroll
    for (int qt = 0; qt < 2; ++qt) {
#pragma unroll
        for (int g = 0; g < 4; ++g)
#pragma unroll
            for (int r = 0; r < 4; ++r) O[qt][g][r] = 0.f;
#pragma unroll
        for (int r = 0; r < 4; ++r) rs[qt][r] = 0.f;
    }

    const int vdh = tid & 63, vkg = tid >> 6;   // V^T staging map

    for (int key0 = 0; key0 < 2048; key0 += 64) {
        __syncthreads();
        // K: [64 key][64 dh], b128 copy
#pragma unroll
        for (int p = 0; p < 2; ++p) {
            int c = p * 256 + tid;
            int row = c >> 3, seg = c & 7;
            *(bf16x8*)&lds_k[row * 74 + seg * 8] =
                *(const bf16x8*)&kb[(key0 + row) * 64 + seg * 8];
        }
        // V^T: lane=dh column reads (coalesced 128B/instr), 2-way LDS writes
        {
            const short* vp = vb + (size_t)(key0 + vkg * 16) * 64 + vdh;
#pragma unroll
            for (int j = 0; j < 16; ++j)
                lds_vt[vdh * 74 + vkg * 16 + j] = vp[j * 64];
        }
        __syncthreads();

        bf16x8 kf[4][2];
#pragma unroll
        for (int kc = 0; kc < 4; ++kc)
#pragma unroll
            for (int h2 = 0; h2 < 2; ++h2)
                kf[kc][h2] = *(bf16x8*)
                    &lds_k[(kc * 16 + l15) * 74 + h2 * 32 + quad * 8];

        // S = Q'K^T (C-layout: row=q, col=key) -> P = exp2(S) -> LDS
#pragma unroll
        for (int qt = 0; qt < 2; ++qt) {
#pragma unroll
            for (int kc = 0; kc < 4; ++kc) {
                fp32x4 s;
#pragma unroll
                for (int r = 0; r < 4; ++r) s[r] = 0.f;
                s = MFMA16(qf[qt][0], kf[kc][0], s);
                s = MFMA16(qf[qt][1], kf[kc][1], s);
#pragma unroll
                for (int r = 0; r < 4; ++r) {
                    float p = __builtin_amdgcn_exp2f(s[r]);
                    rs[qt][r] += p;
                    lds_p[((wv * 2 + qt) * 16 + quad * 4 + r) * 74
                          + kc * 16 + l15] = f2bf(p);
                }
            }
        }
        __threadfence_block();   // per-wave LDS RAW ordering; no barrier needed

        bf16x8 pf[2][2];
#pragma unroll
        for (int qt = 0; qt < 2; ++qt)
#pragma unroll
            for (int ks = 0; ks < 2; ++ks)
                pf[qt][ks] = *(bf16x8*)
                    &lds_p[((wv * 2 + qt) * 16 + l15) * 74 + ks * 32 + quad * 8];
#pragma unroll
        for (int g = 0; g < 4; ++g)
#pragma unroll
            for (int ks = 0; ks < 2; ++ks) {
                bf16x8 vf = *(bf16x8*)
                    &lds_vt[(g * 16 + l15) * 74 + ks * 32 + quad * 8];
#pragma unroll
                for (int qt = 0; qt < 2; ++qt)
                    O[qt][g] = MFMA16(pf[qt][ks], vf, O[qt][g]);
            }
    }

    const int b = bh >> 4, h = bh & 15;
#pragma unroll
    for (int qt = 0; qt < 2; ++qt)
#pragma unroll
        for (int r = 0; r < 4; ++r) {
            float t = rs[qt][r];
            t += __shfl_xor(t, 1);
            t += __shfl_xor(t, 2);
            t += __shfl_xor(t, 4);
            t += __shfl_xor(t, 8);
            float inv = 1.f / t;
            int qq  = q0 + qt * 16 + quad * 4 + r;
            int row = b * 2048 + qq;
#pragma unroll
            for (int g = 0; g < 4; ++g) {
                int col = h * 64 + g * 16 + l15;
                ctx[row * 1024 + col] = f2bf(O[qt][g][r] * inv);
            }
        }
}

extern "C" void kernel_launch(void* const* d_in, const int* in_sizes, int n_in,
                              void* d_out, int out_size, void* d_ws, size_t ws_size,
                              hipStream_t stream) {
    const float* Q  = (const float*)d_in[0];
    const float* K  = (const float*)d_in[1];
    const float* V  = (const float*)d_in[2];
    const float* Wq = (const float*)d_in[3];
    const float* bq = (const float*)d_in[4];
    const float* Wk = (const float*)d_in[5];
    const float* bk = (const float*)d_in[6];
    const float* Wv = (const float*)d_in[7];
    const float* bv = (const float*)d_in[8];
    const float* Wo = (const float*)d_in[9];
    const float* bo = (const float*)d_in[10];

    const size_t M4 = 4ull * 1024 * 1024;       // shorts per 8 MB
    short* wbt  = (short*)d_ws;                 // ws[0,8) MB
    short* vbuf = (short*)d_ws + M4;            // ws[8,16)
    short* cbuf = (short*)d_ws + 2 * M4;        // ws[16,24)
    const bool big = ws_size >= 32ull * 1024 * 1024;

    // Path A (big ws): xq in cbuf region (consumed before attention writes
    // cbuf), xk in d_out upper half, qbuf in d_out lower, kbuf in ws[24,32).
    // Path B: fp32 staging everywhere, qbuf/kbuf both in d_out.
    short* xq   = cbuf;
    short* xk   = (short*)d_out + M4;
    short* qbuf = (short*)d_out;
    short* kbuf = big ? (short*)d_ws + 3 * M4 : (short*)d_out + M4;

    dim3 blk(256);
    hipLaunchKernelGGL(prepass, dim3(16, 16, big ? 6 : 4), blk, 0, stream,
                       Wq, Wk, Wv, Wo, wbt, Q, K, xq, xk);

    const float QSC = 0.125f * 1.44269504088896340736f;  // fold scale*log2e
    GArgs g1;
    g1.X[0] = big ? (const void*)xq : (const void*)Q;
    g1.X[1] = big ? (const void*)xk : (const void*)K;
    g1.X[2] = V;
    g1.W = wbt;
    g1.bias[0] = bq; g1.bias[1] = bk; g1.bias[2] = bv;
    g1.out[0] = qbuf; g1.out[1] = kbuf; g1.out[2] = vbuf;
    g1.abf[0] = big; g1.abf[1] = big; g1.abf[2] = 0;
    g1.osc[0] = QSC; g1.osc[1] = 1.f; g1.osc[2] = 1.f;
    hipLaunchKernelGGL((gemm128<true>), dim3(8, 32, 3), blk, 0, stream, g1);

    hipLaunchKernelGGL(attention128, dim3(16, 32), blk, 0, stream,
                       qbuf, kbuf, vbuf, cbuf);

    GArgs g2;
    g2.X[0] = cbuf; g2.X[1] = cbuf; g2.X[2] = cbuf;
    g2.W = wbt + 3 * 1024 * 1024;
    g2.bias[0] = bo; g2.bias[1] = bo; g2.bias[2] = bo;
    g2.out[0] = d_out; g2.out[1] = d_out; g2.out[2] = d_out;
    g2.abf[0] = 1; g2.abf[1] = 1; g2.abf[2] = 1;
    g2.osc[0] = 1.f; g2.osc[1] = 1.f; g2.osc[2] = 1.f;
    hipLaunchKernelGGL((gemm128<false>), dim3(8, 32, 1), blk, 0, stream, g2);
}